// Round 1
// baseline (1298.006 us; speedup 1.0000x reference)
//
#include <hip/hip_runtime.h>
#include <math.h>

#define N_TOK 8192
#define C_DIM 1024
#define NEXP 8
#define CAP 2560
#define NASSIGN (2 * N_TOK)

// ---------------------------------------------------------------------------
// Kernel 1: gating — logits = x @ w_g^T, top-2, softmax over the top-2.
// One wave (64 lanes) per token. w_g (32 KB) staged in LDS as float4.
// fp64 accumulation so the expert ranking matches the numpy reference even
// near ties (f64 accumulate of f32 products ~1e-15 rel error).
// ---------------------------------------------------------------------------
__global__ __launch_bounds__(256) void gate_kernel(const float* __restrict__ x,
                                                   const float* __restrict__ wg,
                                                   int* __restrict__ epair,
                                                   float* __restrict__ p1o,
                                                   float* __restrict__ p2o) {
    __shared__ float4 wls[NEXP * 256];  // 32 KB
    const int tid = threadIdx.x;
    const float4* wg4 = (const float4*)wg;
    for (int i = tid; i < NEXP * 256; i += 256) wls[i] = wg4[i];
    __syncthreads();

    const int wave = tid >> 6;
    const int lane = tid & 63;
    const int n = blockIdx.x * 4 + wave;
    const float4* x4 = (const float4*)(x + (size_t)n * C_DIM);

    double acc[NEXP];
#pragma unroll
    for (int e = 0; e < NEXP; ++e) acc[e] = 0.0;

#pragma unroll
    for (int c = 0; c < 4; ++c) {
        float4 xv = x4[c * 64 + lane];
#pragma unroll
        for (int e = 0; e < NEXP; ++e) {
            float4 wv = wls[e * 256 + c * 64 + lane];
            acc[e] = fma((double)xv.x, (double)wv.x, acc[e]);
            acc[e] = fma((double)xv.y, (double)wv.y, acc[e]);
            acc[e] = fma((double)xv.z, (double)wv.z, acc[e]);
            acc[e] = fma((double)xv.w, (double)wv.w, acc[e]);
        }
    }

    // wave-64 butterfly reduction of the 8 accumulators
#pragma unroll
    for (int off = 32; off >= 1; off >>= 1) {
#pragma unroll
        for (int e = 0; e < NEXP; ++e) acc[e] += __shfl_xor(acc[e], off);
    }

    if (lane == 0) {
        // top-2 with jax.lax.top_k tie-break (lower index first)
        double v1 = -1e300, v2 = -1e300;
        int i1 = 0, i2 = 0;
#pragma unroll
        for (int e = 0; e < NEXP; ++e) {
            double v = acc[e];
            if (v > v1) { v2 = v1; i2 = i1; v1 = v; i1 = e; }
            else if (v > v2) { v2 = v; i2 = e; }
        }
        double z = exp(v2 - v1);          // <= 1
        double inv = 1.0 / (1.0 + z);
        epair[n] = i1 | (i2 << 8);
        p1o[n] = (float)inv;
        p2o[n] = (float)(z * inv);
    }
}

// ---------------------------------------------------------------------------
// Kernel 2: priority-ordered rank via prefix count. Assignment order is
// k-major (all 1st choices for n=0..N-1, then all 2nd choices). 8 experts
// packed as 16-bit fields into two u64s; single-block Hillis-Steele scan.
// Also emits used_capacity[e] = min(total[e], CAP) as float.
// ---------------------------------------------------------------------------
__global__ __launch_bounds__(1024) void scan_kernel(const int* __restrict__ epair,
                                                    int* __restrict__ rank,
                                                    float* __restrict__ used_cap) {
    __shared__ unsigned long long slo[1024];
    __shared__ unsigned long long shi[1024];
    const int t = threadIdx.x;

    int evals[16];
    unsigned long long lo = 0, hi = 0;
#pragma unroll
    for (int j = 0; j < 16; ++j) {
        int i = t * 16 + j;
        int n = i & (N_TOK - 1);
        int pr = epair[n];
        int e = (i >= N_TOK) ? ((pr >> 8) & 0xff) : (pr & 0xff);
        evals[j] = e;
        unsigned long long inc = 1ULL << (16 * (e & 3));
        if (e < 4) lo += inc; else hi += inc;
    }
    slo[t] = lo;
    shi[t] = hi;
    __syncthreads();

    for (int d = 1; d < 1024; d <<= 1) {
        unsigned long long alo = 0, ahi = 0;
        if (t >= d) { alo = slo[t - d]; ahi = shi[t - d]; }
        __syncthreads();
        if (t >= d) { slo[t] += alo; shi[t] += ahi; }
        __syncthreads();
    }

    unsigned long long rlo = (t > 0) ? slo[t - 1] : 0ULL;
    unsigned long long rhi = (t > 0) ? shi[t - 1] : 0ULL;
#pragma unroll
    for (int j = 0; j < 16; ++j) {
        int e = evals[j];
        int sh = 16 * (e & 3);
        int r = (int)(((e < 4 ? rlo : rhi) >> sh) & 0xffff);
        rank[t * 16 + j] = r;
        if (e < 4) rlo += 1ULL << sh; else rhi += 1ULL << sh;
    }

    if (t == 1023) {
        unsigned long long tlo = slo[1023], thi = shi[1023];
#pragma unroll
        for (int e = 0; e < NEXP; ++e) {
            int c = (int)(((e < 4 ? tlo : thi) >> (16 * (e & 3))) & 0xffff);
            used_cap[e] = (float)(c < CAP ? c : CAP);
        }
    }
}

// ---------------------------------------------------------------------------
// Kernel 3: scatter the kept assignments into cb_weight / sec_mask.
// ---------------------------------------------------------------------------
__global__ __launch_bounds__(256) void scatter_kernel(const int* __restrict__ epair,
                                                      const float* __restrict__ p1,
                                                      const float* __restrict__ p2,
                                                      const int* __restrict__ rank,
                                                      float* __restrict__ cb,
                                                      float* __restrict__ mask) {
    int i = blockIdx.x * 256 + threadIdx.x;
    if (i >= NASSIGN) return;
    int n = i & (N_TOK - 1);
    int pr = epair[n];
    int r = rank[i];
    int e;
    float p;
    if (i >= N_TOK) { e = (pr >> 8) & 0xff; p = p2[n]; }
    else            { e = pr & 0xff;        p = p1[n]; }
    if (r < CAP) {
        size_t idx = (size_t)n * (NEXP * CAP) + (size_t)e * CAP + (size_t)r;
        cb[idx]   = p;
        mask[idx] = 1.0f;
    }
}

extern "C" void kernel_launch(void* const* d_in, const int* in_sizes, int n_in,
                              void* d_out, int out_size, void* d_ws, size_t ws_size,
                              hipStream_t stream) {
    const float* x  = (const float*)d_in[0];
    const float* wg = (const float*)d_in[1];

    float* out  = (float*)d_out;
    float* used = out;                                    // [8]
    float* cb   = out + NEXP;                             // [N, E, CAP]
    float* mask = cb + (size_t)N_TOK * NEXP * CAP;        // [N, E, CAP]

    int*   epair = (int*)d_ws;                            // [N]
    float* p1    = (float*)d_ws + N_TOK;                  // [N]
    float* p2    = (float*)d_ws + 2 * N_TOK;              // [N]
    int*   rank  = (int*)d_ws + 3 * N_TOK;                // [2N]

    // Zero the whole output (it is re-poisoned before every launch).
    hipMemsetAsync(d_out, 0, (size_t)out_size * sizeof(float), stream);

    gate_kernel<<<N_TOK / 4, 256, 0, stream>>>(x, wg, epair, p1, p2);
    scan_kernel<<<1, 1024, 0, stream>>>(epair, rank, used);
    scatter_kernel<<<(NASSIGN + 255) / 256, 256, 0, stream>>>(epair, p1, p2, rank, cb, mask);
}